// Round 20
// baseline (509.263 us; speedup 1.0000x reference)
//
#include <hip/hip_runtime.h>
#include <math.h>

// MoE top-2/8: prep(route+w1T) -> lists -> grouped GEMM1 (gelu) [+tail w2T]
//   -> grouped GEMM2 (mixed-granularity K-split) -> combine
// Shapes fixed: N=8192 tokens, C=1024, H=4096, E=8.
// FFN GEMMs: 256x256 tile, BK=64, 8 waves, 8-phase counted-vmcnt schedule (m201 template).
// R20: revert to R18's proven BK=64 engine (R19's BK=32 had a barrier-motion race AND
//      guaranteed >=32-VGPR spill at 2 blk/CU: acc128+af16+bf16 > 128 cap — dead end).
//      New: heavy ffn2 blocks no longer zero-store companion slices (67MB); odd
//      quarter-slices are hipMemsetAsync'd once per launch (32MB, stream-ordered).

#define NTOK 8192
#define CDIM 1024
#define HDIM 4096
#define NEXP 8
#define MAXT2 71                   // worst-case sum over experts of ceil(cnt/256)
#define MAXROWS2 (MAXT2 * 256)
#define G1BLK (MAXT2 * 16)         // 1136 GEMM blocks in ffn1 grid
#define TRBLK 512                  // w2-transpose tail blocks (8 e * 64 row-chunks)
#define G2BLK 624                  // ffn2 max blocks: 512 heavy + 2*(568-512) light

typedef unsigned short u16;
typedef __attribute__((ext_vector_type(8))) _Float16 half8;
typedef __attribute__((ext_vector_type(4))) float f32x4;

__device__ __forceinline__ u16 f2h(float f) {
    union { _Float16 h; u16 u; } cv; cv.h = (_Float16)f; return cv.u;
}
__device__ __forceinline__ float h2f(u16 u) {
    union { u16 u; _Float16 h; } cv; cv.u = u; return (float)cv.h;
}
__device__ __forceinline__ void gll16(const u16* g, u16* l) {
    __builtin_amdgcn_global_load_lds((__attribute__((address_space(1))) void*)(g),
                                     (__attribute__((address_space(3))) void*)(l),
                                     16, 0, 0);
}
// exact-GELU via A&S 7.1.26 erf approx, |err(erf)| <= 1.5e-7
__device__ __forceinline__ float gelu_f(float v) {
    float u = 0.70710678118654752f * v;
    float au = fabsf(u);
    float t = __builtin_amdgcn_rcpf(1.0f + 0.3275911f * au);
    float p = t * (0.254829592f + t * (-0.284496736f + t * (1.421413741f +
              t * (-1.453152027f + t * 1.061405429f))));
    float ea = __expf(-au * au);
    float er = 1.0f - p * ea;
    er = (u < 0.f) ? -er : er;
    return 0.5f * v * (1.0f + er);
}
// bijective XCD-chunked remap over nact active blocks (m204)
__device__ __forceinline__ int xcd_remap(int lid, int nact) {
    int q = nact >> 3, r = nact & 7;
    int xcd = lid & 7, pos = lid >> 3;
    return (xcd < r) ? (xcd * (q + 1) + pos) : (r * (q + 1) + (xcd - r) * q + pos);
}
__device__ __forceinline__ int sched_nt(const int* __restrict__ cnt8) {
    int at = 0;
#pragma unroll
    for (int q = 0; q < NEXP; ++q) at += (cnt8[q] + 255) >> 8;
    return at;
}
__device__ __forceinline__ void sched_tile(const int* __restrict__ cnt8, int t,
                                           int& e, int& rt, int& prow, int& cnte) {
    int at = 0, ar = 0; e = -1; rt = 0; prow = 0; cnte = 0;
#pragma unroll
    for (int q = 0; q < NEXP; ++q) {
        int c = cnt8[q]; int ti = (c + 255) >> 8;
        if (e < 0 && t < at + ti) { e = q; rt = t - at; prow = ar; cnte = c; }
        at += ti; ar += ti * 256;
    }
}

// ---------------- routing (atomic-free)
__device__ __forceinline__ void route_body(
    int blk, const float* __restrict__ x, const float* __restrict__ gw,
    const float* __restrict__ gb, u16* __restrict__ xh,
    float2* __restrict__ rtw, int* __restrict__ choice)
{
    int tid = threadIdx.x, lane = tid & 63, wid = tid >> 6;
    int tok = blk * 4 + wid;
    const float* xr = x + (size_t)tok * CDIM;
    float a[NEXP];
#pragma unroll
    for (int e = 0; e < NEXP; e++) a[e] = 0.f;
#pragma unroll
    for (int j = 0; j < 4; j++) {
        int k0 = j * 256 + lane * 4;
        float4 xv = *reinterpret_cast<const float4*>(xr + k0);
        ushort4 hv;
        hv.x = f2h(xv.x); hv.y = f2h(xv.y); hv.z = f2h(xv.z); hv.w = f2h(xv.w);
        *reinterpret_cast<ushort4*>(xh + (size_t)tok * CDIM + k0) = hv;
        const float* gr = gw + (size_t)k0 * NEXP;
#pragma unroll
        for (int t = 0; t < 4; t++) {
            float xs = (t == 0) ? xv.x : (t == 1) ? xv.y : (t == 2) ? xv.z : xv.w;
            float4 g0 = *reinterpret_cast<const float4*>(gr + t * 8);
            float4 g1 = *reinterpret_cast<const float4*>(gr + t * 8 + 4);
            a[0] += xs * g0.x; a[1] += xs * g0.y; a[2] += xs * g0.z; a[3] += xs * g0.w;
            a[4] += xs * g1.x; a[5] += xs * g1.y; a[6] += xs * g1.z; a[7] += xs * g1.w;
        }
    }
#pragma unroll
    for (int ofs = 32; ofs >= 1; ofs >>= 1) {
#pragma unroll
        for (int e = 0; e < NEXP; e++) a[e] += __shfl_xor(a[e], ofs, 64);
    }
    if (lane == 0) {
#pragma unroll
        for (int e = 0; e < NEXP; e++) a[e] += gb[e];
        int i0 = 0; float v0 = a[0];
#pragma unroll
        for (int e = 1; e < NEXP; e++) if (a[e] > v0) { v0 = a[e]; i0 = e; }
        int i1 = -1; float v1 = -3.4e38f;
#pragma unroll
        for (int e = 0; e < NEXP; e++) if (e != i0 && a[e] > v1) { v1 = a[e]; i1 = e; }
        float t = expf(v1 - v0);
        float w0 = 1.f / (1.f + t);
        rtw[tok] = make_float2(w0, t * w0);
        choice[tok] = i0 | (i1 << 4);
    }
}

// 64x256 fp32 -> fp16 transpose (tid passed in; 256 lanes)
__device__ __forceinline__ void transpose_body4t(
    int bx, int by, int e, const float* __restrict__ src, u16* __restrict__ dst,
    int R, int S, u16* tile, int tid)
{
    const float* se = src + (size_t)e * R * S;
    u16* de = dst + (size_t)e * R * S;
    int c0 = bx * 256, r0 = by * 64;
    int bc = tid & 15, br = tid >> 4;
    int wr = tid & 15, cr = tid >> 4;
#pragma unroll
    for (int q = 0; q < 4; ++q) {
        int cq = c0 + q * 64;
        u16 h[4][4];
#pragma unroll
        for (int i = 0; i < 4; i++) {
            float4 v = *reinterpret_cast<const float4*>(
                se + (size_t)(r0 + 4 * br + i) * S + cq + 4 * bc);
            h[i][0] = f2h(v.x); h[i][1] = f2h(v.y); h[i][2] = f2h(v.z); h[i][3] = f2h(v.w);
        }
        if (q) __syncthreads();
#pragma unroll
        for (int j = 0; j < 4; j++) {
            ushort4 w;
            w.x = h[0][j]; w.y = h[1][j]; w.z = h[2][j]; w.w = h[3][j];
            int row = 4 * bc + j;
            *reinterpret_cast<ushort4*>(&tile[row * 64 + ((br ^ (row & 15)) << 2)]) = w;
        }
        __syncthreads();
#pragma unroll
        for (int i = 0; i < 4; i++) {
            int row = cr + 16 * i;
            ushort4 o = *reinterpret_cast<const ushort4*>(
                &tile[row * 64 + ((wr ^ (row & 15)) << 2)]);
            *reinterpret_cast<ushort4*>(de + (size_t)(cq + row) * R + r0 + 4 * wr) = o;
        }
    }
}

// ---------------- prep: z=0 routing, z=1 transpose w1
__global__ __launch_bounds__(256) void k_prep(
    const float* __restrict__ x, const float* __restrict__ gw,
    const float* __restrict__ gb, u16* __restrict__ xh,
    float2* __restrict__ rtw, int* __restrict__ choice,
    const float* __restrict__ w1, u16* __restrict__ w1t)
{
    __shared__ __align__(16) u16 tile[64 * 64];
    int z = blockIdx.z;
    int bxf = blockIdx.x;
    if (z == 0) {
        route_body(bxf, x, gw, gb, xh, rtw, choice);
    } else {
        int e = bxf >> 8, r = bxf & 255;
        transpose_body4t(r & 15, r >> 4, e, w1, w1t, CDIM, HDIM, tile, threadIdx.x);
    }
}

// ---------------- lists: per-expert token-ordered compaction
__global__ __launch_bounds__(256) void k_lists(
    const int* __restrict__ choice, int* __restrict__ cnt, int* __restrict__ lists)
{
    __shared__ int wsum[4];
    __shared__ int base;
    int e = blockIdx.x;
    int tid = threadIdx.x, lane = tid & 63, wv = tid >> 6;
    if (tid == 0) base = 0;
    __syncthreads();
    for (int t0 = 0; t0 < NTOK; t0 += 256) {
        int tok = t0 + tid;
        int ch = choice[tok];
        int i0 = ch & 15, i1 = (ch >> 4) & 15;
        int pred = (i0 == e || i1 == e) ? 1 : 0;
        int entry = tok * 2 + ((i0 == e) ? 0 : 1);
        unsigned long long m = __ballot(pred);
        int wpre = __popcll(m & ((1ull << lane) - 1ull));
        if (lane == 0) wsum[wv] = __popcll(m);
        __syncthreads();
        int pre = wpre;
#pragma unroll
        for (int w2 = 0; w2 < 4; ++w2) if (w2 < wv) pre += wsum[w2];
        int tot = wsum[0] + wsum[1] + wsum[2] + wsum[3];
        if (pred) lists[e * NTOK + base + pre] = entry;
        __syncthreads();
        if (tid == 0) base += tot;
        __syncthreads();
    }
    if (tid == 0) cnt[e] = base;
}

// ======== 8-phase 256x256 BK=64 GEMM engine (proven R18) ========
#define DSA(BUF, QR) do { \
    _Pragma("unroll") for (int fm_ = 0; fm_ < 4; ++fm_) { \
        af[fm_][0] = HA[aIdx0 + ((QR) * 4 + fm_) * 128 + (BUF) * 2048]; \
        af[fm_][1] = HA[aIdx1 + ((QR) * 4 + fm_) * 128 + (BUF) * 2048]; \
    } } while (0)

#define DSB(BUF, QC) do { \
    _Pragma("unroll") for (int fn_ = 0; fn_ < 2; ++fn_) { \
        bf[QC][fn_][0] = HB[bIdx0 + ((QC) * 2 + fn_) * 128 + (BUF) * 2048]; \
        bf[QC][fn_][1] = HB[bIdx1 + ((QC) * 2 + fn_) * 128 + (BUF) * 2048]; \
    } } while (0)

#define FFN_MFMA(QR, QC) do { \
    __builtin_amdgcn_s_setprio(1); \
    _Pragma("unroll") for (int fm_ = 0; fm_ < 4; ++fm_) \
    _Pragma("unroll") for (int fn_ = 0; fn_ < 2; ++fn_) { \
        acc[(QR) * 4 + fm_][(QC) * 2 + fn_] = __builtin_amdgcn_mfma_f32_16x16x32_f16( \
            bf[QC][fn_][0], af[fm_][0], acc[(QR) * 4 + fm_][(QC) * 2 + fn_], 0, 0, 0); \
        acc[(QR) * 4 + fm_][(QC) * 2 + fn_] = __builtin_amdgcn_mfma_f32_16x16x32_f16( \
            bf[QC][fn_][1], af[fm_][1], acc[(QR) * 4 + fm_][(QC) * 2 + fn_], 0, 0, 0); \
    } \
    __builtin_amdgcn_s_setprio(0); } while (0)

#define PUB()  __builtin_amdgcn_s_barrier()
#define PUBG() do { __builtin_amdgcn_s_barrier(); \
                    __builtin_amdgcn_sched_barrier(0); } while (0)
#define VMW4() asm volatile("s_waitcnt vmcnt(4)" ::: "memory")

#define STA(BUF, H) do { \
    gll16(pa[H][0], ldsA + (BUF) * 16384 + ((H) * 128 + wv * 16) * 64); pa[H][0] += 64; \
    gll16(pa[H][1], ldsA + (BUF) * 16384 + ((H) * 128 + wv * 16 + 8) * 64); pa[H][1] += 64; } while (0)

#define STB(BUF, H) do { \
    gll16(pb[H][0], ldsB + (BUF) * 16384 + ((H) * 128 + wv * 16) * 64); pb[H][0] += 64; \
    gll16(pb[H][1], ldsB + (BUF) * 16384 + ((H) * 128 + wv * 16 + 8) * 64); pb[H][1] += 64; } while (0)

#define FFN_KLOOP(NK) do { \
    STB(0, 0); STB(0, 1); STA(0, 0); STA(0, 1); STB(1, 0); STB(1, 1); \
    VMW4(); PUBG(); \
    for (int i_ = 0; i_ < (NK) / 2; ++i_) { \
        DSA(0, 0); DSB(0, 0); STA(1, 0);  PUB(); FFN_MFMA(0, 0); PUB(); \
        DSB(0, 1); STA(1, 1);             PUB(); FFN_MFMA(0, 1); PUBG(); \
        DSA(0, 1); STB(0, 0);             PUB(); FFN_MFMA(1, 0); PUB(); \
        STB(0, 1); VMW4();                PUB(); FFN_MFMA(1, 1); PUBG(); \
        DSA(1, 0); DSB(1, 0); STA(0, 0);  PUB(); FFN_MFMA(0, 0); PUB(); \
        DSB(1, 1); STA(0, 1);             PUB(); FFN_MFMA(0, 1); PUBG(); \
        DSA(1, 1); STB(1, 0);             PUB(); FFN_MFMA(1, 0); PUB(); \
        STB(1, 1); VMW4();                PUB(); FFN_MFMA(1, 1); PUBG(); \
    } } while (0)

// ---------------- grouped GEMM1 + w2-transpose tail blocks
__global__ __launch_bounds__(512, 2) void k_ffn1(
    const u16* __restrict__ xh, const u16* __restrict__ w1t,
    const float* __restrict__ b1, u16* __restrict__ hbuf,
    const int* __restrict__ ctrl, const int* __restrict__ lists,
    const float* __restrict__ w2, u16* __restrict__ w2t)
{
    extern __shared__ __align__(16) u16 lds[];
    int lid = blockIdx.x;
    int tid = threadIdx.x;
    if (lid >= G1BLK) {
        int tlid = lid - G1BLK;
        int e = tlid >> 6, by = tlid & 63;
        int half = tid >> 8, t2 = tid & 255;
        u16* mytile = lds + half * 4096;
#pragma unroll
        for (int c4 = 0; c4 < 2; ++c4)
            transpose_body4t(half * 2 + c4, by, e, w2, w2t, HDIM, CDIM, mytile, t2);
        return;
    }
    u16* ldsA = lds;                   // [2][256*64]
    u16* ldsB = lds + 2 * 256 * 64;    // [2][256*64]
    const half8* HA = reinterpret_cast<const half8*>(ldsA);
    const half8* HB = reinterpret_cast<const half8*>(ldsB);
    const int* cnt8 = ctrl + 8;
    int nt = sched_nt(cnt8);
    int nact = nt * 16;
    if (lid >= nact) return;
    int w = xcd_remap(lid, nact);
    int nt8 = nt * 8;
    int byh = w / nt8;
    int rem = w - byh * nt8;
    int t = rem >> 3;
    int by = byh * 8 + (rem & 7);
    int e, rt, prow, cnte;
    sched_tile(cnt8, t, e, rt, prow, cnte);
    int n0 = by * 256;
    int lane = tid & 63, wv = tid >> 6;
    int wm = wv >> 2, wn = wv & 3;
    int lr = lane >> 3;
    int chunk = (lane & 7) ^ lr;
    const int* lrow = lists + e * NTOK + rt * 256;
    int first_ent = lists[e * NTOK];
    const u16* pa[2][2]; const u16* pb[2][2];
#pragma unroll
    for (int h = 0; h < 2; ++h)
#pragma unroll
        for (int g = 0; g < 2; ++g) {
            int r = h * 128 + wv * 16 + g * 8 + lr;
            int ent = (rt * 256 + r < cnte) ? lrow[r] : first_ent;
            int tok = ent >> 1;
            pa[h][g] = xh + (size_t)tok * CDIM + chunk * 8;
            pb[h][g] = w1t + (size_t)e * HDIM * CDIM + (size_t)(n0 + r) * CDIM + chunk * 8;
        }
    int aIdx0 = wm * 1024 + (lane & 15) * 8 + ((lane >> 4) ^ (lane & 7));
    int aIdx1 = wm * 1024 + (lane & 15) * 8 + (((lane >> 4) + 4) ^ (lane & 7));
    int bIdx0 = wn * 512 + (lane & 15) * 8 + ((lane >> 4) ^ (lane & 7));
    int bIdx1 = wn * 512 + (lane & 15) * 8 + (((lane >> 4) + 4) ^ (lane & 7));
    f32x4 acc[8][4];
#pragma unroll
    for (int m = 0; m < 8; ++m)
#pragma unroll
        for (int n = 0; n < 4; ++n) acc[m][n] = f32x4{0.f, 0.f, 0.f, 0.f};
    half8 af[4][2], bf[2][2][2];

    FFN_KLOOP(16);   // K = 1024 = 16 tiles of 64

    const f32x4* b1v = reinterpret_cast<const f32x4*>(b1 + (size_t)e * HDIM);
    f32x4 bv[4];
#pragma unroll
    for (int n = 0; n < 4; ++n)
        bv[n] = b1v[(n0 + wn * 64 + n * 16) / 4 + (lane >> 4)];
#pragma unroll
    for (int m = 0; m < 8; ++m) {
        int grow = prow + rt * 256 + wm * 128 + m * 16 + (lane & 15);
        u16* hr = hbuf + (size_t)grow * HDIM + n0 + wn * 64 + (lane >> 4) * 4;
#pragma unroll
        for (int n = 0; n < 4; ++n) {
            ushort4 o;
#pragma unroll
            for (int j = 0; j < 4; ++j)
                ((u16*)&o)[j] = f2h(gelu_f(acc[m][n][j] + bv[n][j]));
            *reinterpret_cast<ushort4*>(hr + n * 16) = o;
        }
    }
}

// ---------------- grouped GEMM2 (mixed K-split): heavy=half-K, light=quarter-K
// Odd quarter-slices are pre-zeroed by hipMemsetAsync; heavy blocks write only
// their own slice (no zero companion stores).
__global__ __launch_bounds__(512, 2) void k_ffn2(
    const u16* __restrict__ hbuf, const u16* __restrict__ w2t,
    const float* __restrict__ b2, u16* __restrict__ ybuf,
    const int* __restrict__ ctrl, const int* __restrict__ lists,
    const float2* __restrict__ rtw)
{
    extern __shared__ __align__(16) u16 lds[];
    u16* ldsA = lds;
    u16* ldsB = lds + 2 * 256 * 64;
    const half8* HA = reinterpret_cast<const half8*>(ldsA);
    const half8* HB = reinterpret_cast<const half8*>(ldsB);
    const int* cnt8 = ctrl + 8;
    int lid = blockIdx.x;
    int nt = sched_nt(cnt8);
    int U = nt * 8;
    int S = (U > 512) ? (U - 512) : 0;
    int Hh = U - S;
    int nact = Hh + 2 * S;
    if (lid >= nact) return;
    bool heavy = lid < Hh;
    int u, qh;
    if (heavy) { u = xcd_remap(lid, Hh); qh = 0; }
    else { int l = lid - Hh; u = Hh + (l >> 1); qh = l & 1; }
    int nt4 = nt * 4;
    int kh = u / nt4;
    int rem = u - kh * nt4;
    int t = rem >> 2;
    int by = rem & 3;
    int e, rt, prow, cnte;
    sched_tile(cnt8, t, e, rt, prow, cnte);
    int n0 = by * 256;
    int koff = kh * 2048 + qh * 1024;
    int tid = threadIdx.x, lane = tid & 63, wv = tid >> 6;
    int wm = wv >> 2, wn = wv & 3;
    int lr = lane >> 3;
    int chunk = (lane & 7) ^ lr;
    int rowbase = prow + rt * 256;
    const u16* pa[2][2]; const u16* pb[2][2];
#pragma unroll
    for (int h = 0; h < 2; ++h)
#pragma unroll
        for (int g = 0; g < 2; ++g) {
            int r = h * 128 + wv * 16 + g * 8 + lr;
            pa[h][g] = hbuf + (size_t)(rowbase + r) * HDIM + koff + chunk * 8;
            pb[h][g] = w2t + (size_t)e * CDIM * HDIM + (size_t)(n0 + r) * HDIM + koff + chunk * 8;
        }
    int aIdx0 = wm * 1024 + (lane & 15) * 8 + ((lane >> 4) ^ (lane & 7));
    int aIdx1 = wm * 1024 + (lane & 15) * 8 + (((lane >> 4) + 4) ^ (lane & 7));
    int bIdx0 = wn * 512 + (lane & 15) * 8 + ((lane >> 4) ^ (lane & 7));
    int bIdx1 = wn * 512 + (lane & 15) * 8 + (((lane >> 4) + 4) ^ (lane & 7));
    f32x4 acc[8][4];
#pragma unroll
    for (int m = 0; m < 8; ++m)
#pragma unroll
        for (int n = 0; n < 4; ++n) acc[m][n] = f32x4{0.f, 0.f, 0.f, 0.f};
    half8 af[4][2], bf[2][2][2];

    if (heavy) { FFN_KLOOP(32); } else { FFN_KLOOP(16); }

    const f32x4* b2v = reinterpret_cast<const f32x4*>(b2 + (size_t)e * CDIM);
    f32x4 bv[4];
#pragma unroll
    for (int n = 0; n < 4; ++n)
        bv[n] = b2v[(n0 + wn * 64 + n * 16) / 4 + (lane >> 4)];
    const int* lrow = lists + e * NTOK;
    const size_t SL = (size_t)NTOK * CDIM;
    int q = 2 * kh + qh;
#pragma unroll
    for (int m = 0; m < 8; ++m) {
        int p = rt * 256 + wm * 128 + m * 16 + (lane & 15);
        bool valid = p < cnte;
        int entry = valid ? lrow[p] : 0;
        float2 wpair = rtw[entry >> 1];
        float wgt = (entry & 1) ? wpair.y : wpair.x;
        size_t base = (size_t)(entry >> 1) * CDIM + n0 + wn * 64 + (lane >> 4) * 4;
        u16* yb = ybuf + ((size_t)((entry & 1) * 4 + q)) * SL + base;
#pragma unroll
        for (int n = 0; n < 4; ++n) {
            f32x4 v = acc[m][n];
            if (koff == 0) v = v + bv[n];
            v = v * wgt;
            ushort4 o;
#pragma unroll
            for (int j = 0; j < 4; ++j) ((u16*)&o)[j] = f2h(v[j]);
            if (valid) *reinterpret_cast<ushort4*>(yb + n * 16) = o;
        }
    }
}

// ---------------- combine: out = sum of 8 fp16 ybuf slices
__global__ __launch_bounds__(256) void k_combine(
    const u16* __restrict__ ybuf, float* __restrict__ out)
{
    size_t i = ((size_t)blockIdx.x * 256 + threadIdx.x) * 4;
    const size_t S = (size_t)NTOK * CDIM;
    float s0 = 0.f, s1 = 0.f, s2 = 0.f, s3 = 0.f;
#pragma unroll
    for (int sl = 0; sl < 8; ++sl) {
        ushort4 h = *reinterpret_cast<const ushort4*>(ybuf + sl * S + i);
        s0 += h2f(h.x); s1 += h2f(h.y); s2 += h2f(h.z); s3 += h2f(h.w);
    }
    f32x4 o; o[0] = s0; o[1] = s1; o[2] = s2; o[3] = s3;
    *reinterpret_cast<f32x4*>(out + i) = o;
}

extern "C" void kernel_launch(void* const* d_in, const int* in_sizes, int n_in,
                              void* d_out, int out_size, void* d_ws, size_t ws_size,
                              hipStream_t stream)
{
    const float* x  = (const float*)d_in[0];
    const float* gw = (const float*)d_in[1];
    const float* gb = (const float*)d_in[2];
    const float* w1 = (const float*)d_in[3];
    const float* b1 = (const float*)d_in[4];
    const float* w2 = (const float*)d_in[5];
    const float* b2 = (const float*)d_in[6];
    float* out = (float*)d_out;
    char* ws = (char*)d_ws;

    size_t off = 0;
    int*    ctrl  = (int*)(ws + off);    off += 4096;
    float2* rtw   = (float2*)(ws + off); off += (size_t)NTOK * 8;
    int*    choice= (int*)(ws + off);    off += (size_t)NTOK * 4;
    int*    lists = (int*)(ws + off);    off += (size_t)NEXP * NTOK * 4;
    u16*    xh    = (u16*)(ws + off);    off += (size_t)NTOK * CDIM * 2;
    u16*    w1t   = (u16*)(ws + off);    off += (size_t)NEXP * CDIM * HDIM * 2;
    u16*    w2t   = (u16*)(ws + off);    off += (size_t)NEXP * CDIM * HDIM * 2;
    u16*    hbuf  = (u16*)(ws + off);    off += (size_t)MAXROWS2 * HDIM * 2;
    u16*    ybuf  = (u16*)(ws + off);    off += (size_t)8 * NTOK * CDIM * 2;
    (void)ws_size; (void)in_sizes; (void)n_in; (void)out_size;

    hipFuncSetAttribute((const void*)k_ffn1, hipFuncAttributeMaxDynamicSharedMemorySize, 131072);
    hipFuncSetAttribute((const void*)k_ffn2, hipFuncAttributeMaxDynamicSharedMemorySize, 131072);

    const size_t SL = (size_t)NTOK * CDIM;   // u16 elements per slice
    // z=0: route (atomic-free); z=1: w1 transpose
    k_prep<<<dim3(2048, 1, 2), 256, 0, stream>>>(x, gw, gb, xh, rtw, choice, w1, w1t);
    k_lists<<<dim3(NEXP), 256, 0, stream>>>(choice, ctrl + 8, lists);
    // pre-zero odd quarter-slices (1,3,5,7) so heavy blocks need no zero-stores
    hipMemsetAsync(ybuf + 1 * SL, 0, SL * 2, stream);
    hipMemsetAsync(ybuf + 3 * SL, 0, SL * 2, stream);
    hipMemsetAsync(ybuf + 5 * SL, 0, SL * 2, stream);
    hipMemsetAsync(ybuf + 7 * SL, 0, SL * 2, stream);
    // GEMM1 blocks [0,1136) + w2-transpose tail blocks [1136,1648)
    k_ffn1<<<dim3(G1BLK + TRBLK), 512, 131072, stream>>>(xh, w1t, b1, hbuf, ctrl, lists,
                                                         w2, w2t);
    k_ffn2<<<dim3(G2BLK), 512, 131072, stream>>>(hbuf, w2t, b2, ybuf, ctrl, lists, rtw);
    k_combine<<<dim3(NTOK * CDIM / 1024), 256, 0, stream>>>(ybuf, out);
}

// Round 21
// 503.862 us; speedup vs baseline: 1.0107x; 1.0107x over previous
//
#include <hip/hip_runtime.h>
#include <math.h>

// MoE top-2/8: prep(route+w1T) -> lists -> grouped GEMM1 (gelu) [+tail w2T]
//   -> grouped GEMM2 (mixed-granularity K-split) -> combine
// Shapes fixed: N=8192 tokens, C=1024, H=4096, E=8.
// FFN GEMMs: 256x256 tile, BK=64, 8 waves, 8-phase counted-vmcnt schedule (m201 template).
// R21: exact revert to R18 (best measured: 504.6us). R20's hipMemsetAsync pre-zero
//      regressed (+4.7us): memsets serialize on the stream (~15-20us exposed), while
//      R18's in-kernel zero companion-stores overlap with ffn2's MFMA. Heavy blocks
//      zero slice 2kh+1 themselves; no memsets.

#define NTOK 8192
#define CDIM 1024
#define HDIM 4096
#define NEXP 8
#define MAXT2 71                   // worst-case sum over experts of ceil(cnt/256)
#define MAXROWS2 (MAXT2 * 256)
#define G1BLK (MAXT2 * 16)         // 1136 GEMM blocks in ffn1 grid
#define TRBLK 512                  // w2-transpose tail blocks (8 e * 64 row-chunks)
#define G2BLK 624                  // ffn2 max blocks: 512 heavy + 2*(568-512) light

typedef unsigned short u16;
typedef __attribute__((ext_vector_type(8))) _Float16 half8;
typedef __attribute__((ext_vector_type(4))) float f32x4;

__device__ __forceinline__ u16 f2h(float f) {
    union { _Float16 h; u16 u; } cv; cv.h = (_Float16)f; return cv.u;
}
__device__ __forceinline__ float h2f(u16 u) {
    union { u16 u; _Float16 h; } cv; cv.u = u; return (float)cv.h;
}
__device__ __forceinline__ void gll16(const u16* g, u16* l) {
    __builtin_amdgcn_global_load_lds((__attribute__((address_space(1))) void*)(g),
                                     (__attribute__((address_space(3))) void*)(l),
                                     16, 0, 0);
}
// exact-GELU via A&S 7.1.26 erf approx, |err(erf)| <= 1.5e-7
__device__ __forceinline__ float gelu_f(float v) {
    float u = 0.70710678118654752f * v;
    float au = fabsf(u);
    float t = __builtin_amdgcn_rcpf(1.0f + 0.3275911f * au);
    float p = t * (0.254829592f + t * (-0.284496736f + t * (1.421413741f +
              t * (-1.453152027f + t * 1.061405429f))));
    float ea = __expf(-au * au);
    float er = 1.0f - p * ea;
    er = (u < 0.f) ? -er : er;
    return 0.5f * v * (1.0f + er);
}
// bijective XCD-chunked remap over nact active blocks (m204)
__device__ __forceinline__ int xcd_remap(int lid, int nact) {
    int q = nact >> 3, r = nact & 7;
    int xcd = lid & 7, pos = lid >> 3;
    return (xcd < r) ? (xcd * (q + 1) + pos) : (r * (q + 1) + (xcd - r) * q + pos);
}
__device__ __forceinline__ int sched_nt(const int* __restrict__ cnt8) {
    int at = 0;
#pragma unroll
    for (int q = 0; q < NEXP; ++q) at += (cnt8[q] + 255) >> 8;
    return at;
}
__device__ __forceinline__ void sched_tile(const int* __restrict__ cnt8, int t,
                                           int& e, int& rt, int& prow, int& cnte) {
    int at = 0, ar = 0; e = -1; rt = 0; prow = 0; cnte = 0;
#pragma unroll
    for (int q = 0; q < NEXP; ++q) {
        int c = cnt8[q]; int ti = (c + 255) >> 8;
        if (e < 0 && t < at + ti) { e = q; rt = t - at; prow = ar; cnte = c; }
        at += ti; ar += ti * 256;
    }
}

// ---------------- routing (atomic-free)
__device__ __forceinline__ void route_body(
    int blk, const float* __restrict__ x, const float* __restrict__ gw,
    const float* __restrict__ gb, u16* __restrict__ xh,
    float2* __restrict__ rtw, int* __restrict__ choice)
{
    int tid = threadIdx.x, lane = tid & 63, wid = tid >> 6;
    int tok = blk * 4 + wid;
    const float* xr = x + (size_t)tok * CDIM;
    float a[NEXP];
#pragma unroll
    for (int e = 0; e < NEXP; e++) a[e] = 0.f;
#pragma unroll
    for (int j = 0; j < 4; j++) {
        int k0 = j * 256 + lane * 4;
        float4 xv = *reinterpret_cast<const float4*>(xr + k0);
        ushort4 hv;
        hv.x = f2h(xv.x); hv.y = f2h(xv.y); hv.z = f2h(xv.z); hv.w = f2h(xv.w);
        *reinterpret_cast<ushort4*>(xh + (size_t)tok * CDIM + k0) = hv;
        const float* gr = gw + (size_t)k0 * NEXP;
#pragma unroll
        for (int t = 0; t < 4; t++) {
            float xs = (t == 0) ? xv.x : (t == 1) ? xv.y : (t == 2) ? xv.z : xv.w;
            float4 g0 = *reinterpret_cast<const float4*>(gr + t * 8);
            float4 g1 = *reinterpret_cast<const float4*>(gr + t * 8 + 4);
            a[0] += xs * g0.x; a[1] += xs * g0.y; a[2] += xs * g0.z; a[3] += xs * g0.w;
            a[4] += xs * g1.x; a[5] += xs * g1.y; a[6] += xs * g1.z; a[7] += xs * g1.w;
        }
    }
#pragma unroll
    for (int ofs = 32; ofs >= 1; ofs >>= 1) {
#pragma unroll
        for (int e = 0; e < NEXP; e++) a[e] += __shfl_xor(a[e], ofs, 64);
    }
    if (lane == 0) {
#pragma unroll
        for (int e = 0; e < NEXP; e++) a[e] += gb[e];
        int i0 = 0; float v0 = a[0];
#pragma unroll
        for (int e = 1; e < NEXP; e++) if (a[e] > v0) { v0 = a[e]; i0 = e; }
        int i1 = -1; float v1 = -3.4e38f;
#pragma unroll
        for (int e = 0; e < NEXP; e++) if (e != i0 && a[e] > v1) { v1 = a[e]; i1 = e; }
        float t = expf(v1 - v0);
        float w0 = 1.f / (1.f + t);
        rtw[tok] = make_float2(w0, t * w0);
        choice[tok] = i0 | (i1 << 4);
    }
}

// 64x256 fp32 -> fp16 transpose (tid passed in; 256 lanes)
__device__ __forceinline__ void transpose_body4t(
    int bx, int by, int e, const float* __restrict__ src, u16* __restrict__ dst,
    int R, int S, u16* tile, int tid)
{
    const float* se = src + (size_t)e * R * S;
    u16* de = dst + (size_t)e * R * S;
    int c0 = bx * 256, r0 = by * 64;
    int bc = tid & 15, br = tid >> 4;
    int wr = tid & 15, cr = tid >> 4;
#pragma unroll
    for (int q = 0; q < 4; ++q) {
        int cq = c0 + q * 64;
        u16 h[4][4];
#pragma unroll
        for (int i = 0; i < 4; i++) {
            float4 v = *reinterpret_cast<const float4*>(
                se + (size_t)(r0 + 4 * br + i) * S + cq + 4 * bc);
            h[i][0] = f2h(v.x); h[i][1] = f2h(v.y); h[i][2] = f2h(v.z); h[i][3] = f2h(v.w);
        }
        if (q) __syncthreads();
#pragma unroll
        for (int j = 0; j < 4; j++) {
            ushort4 w;
            w.x = h[0][j]; w.y = h[1][j]; w.z = h[2][j]; w.w = h[3][j];
            int row = 4 * bc + j;
            *reinterpret_cast<ushort4*>(&tile[row * 64 + ((br ^ (row & 15)) << 2)]) = w;
        }
        __syncthreads();
#pragma unroll
        for (int i = 0; i < 4; i++) {
            int row = cr + 16 * i;
            ushort4 o = *reinterpret_cast<const ushort4*>(
                &tile[row * 64 + ((wr ^ (row & 15)) << 2)]);
            *reinterpret_cast<ushort4*>(de + (size_t)(cq + row) * R + r0 + 4 * wr) = o;
        }
    }
}

// ---------------- prep: z=0 routing, z=1 transpose w1
__global__ __launch_bounds__(256) void k_prep(
    const float* __restrict__ x, const float* __restrict__ gw,
    const float* __restrict__ gb, u16* __restrict__ xh,
    float2* __restrict__ rtw, int* __restrict__ choice,
    const float* __restrict__ w1, u16* __restrict__ w1t)
{
    __shared__ __align__(16) u16 tile[64 * 64];
    int z = blockIdx.z;
    int bxf = blockIdx.x;
    if (z == 0) {
        route_body(bxf, x, gw, gb, xh, rtw, choice);
    } else {
        int e = bxf >> 8, r = bxf & 255;
        transpose_body4t(r & 15, r >> 4, e, w1, w1t, CDIM, HDIM, tile, threadIdx.x);
    }
}

// ---------------- lists: per-expert token-ordered compaction
__global__ __launch_bounds__(256) void k_lists(
    const int* __restrict__ choice, int* __restrict__ cnt, int* __restrict__ lists)
{
    __shared__ int wsum[4];
    __shared__ int base;
    int e = blockIdx.x;
    int tid = threadIdx.x, lane = tid & 63, wv = tid >> 6;
    if (tid == 0) base = 0;
    __syncthreads();
    for (int t0 = 0; t0 < NTOK; t0 += 256) {
        int tok = t0 + tid;
        int ch = choice[tok];
        int i0 = ch & 15, i1 = (ch >> 4) & 15;
        int pred = (i0 == e || i1 == e) ? 1 : 0;
        int entry = tok * 2 + ((i0 == e) ? 0 : 1);
        unsigned long long m = __ballot(pred);
        int wpre = __popcll(m & ((1ull << lane) - 1ull));
        if (lane == 0) wsum[wv] = __popcll(m);
        __syncthreads();
        int pre = wpre;
#pragma unroll
        for (int w2 = 0; w2 < 4; ++w2) if (w2 < wv) pre += wsum[w2];
        int tot = wsum[0] + wsum[1] + wsum[2] + wsum[3];
        if (pred) lists[e * NTOK + base + pre] = entry;
        __syncthreads();
        if (tid == 0) base += tot;
        __syncthreads();
    }
    if (tid == 0) cnt[e] = base;
}

// ======== 8-phase 256x256 BK=64 GEMM engine (proven R18) ========
#define DSA(BUF, QR) do { \
    _Pragma("unroll") for (int fm_ = 0; fm_ < 4; ++fm_) { \
        af[fm_][0] = HA[aIdx0 + ((QR) * 4 + fm_) * 128 + (BUF) * 2048]; \
        af[fm_][1] = HA[aIdx1 + ((QR) * 4 + fm_) * 128 + (BUF) * 2048]; \
    } } while (0)

#define DSB(BUF, QC) do { \
    _Pragma("unroll") for (int fn_ = 0; fn_ < 2; ++fn_) { \
        bf[QC][fn_][0] = HB[bIdx0 + ((QC) * 2 + fn_) * 128 + (BUF) * 2048]; \
        bf[QC][fn_][1] = HB[bIdx1 + ((QC) * 2 + fn_) * 128 + (BUF) * 2048]; \
    } } while (0)

#define FFN_MFMA(QR, QC) do { \
    __builtin_amdgcn_s_setprio(1); \
    _Pragma("unroll") for (int fm_ = 0; fm_ < 4; ++fm_) \
    _Pragma("unroll") for (int fn_ = 0; fn_ < 2; ++fn_) { \
        acc[(QR) * 4 + fm_][(QC) * 2 + fn_] = __builtin_amdgcn_mfma_f32_16x16x32_f16( \
            bf[QC][fn_][0], af[fm_][0], acc[(QR) * 4 + fm_][(QC) * 2 + fn_], 0, 0, 0); \
        acc[(QR) * 4 + fm_][(QC) * 2 + fn_] = __builtin_amdgcn_mfma_f32_16x16x32_f16( \
            bf[QC][fn_][1], af[fm_][1], acc[(QR) * 4 + fm_][(QC) * 2 + fn_], 0, 0, 0); \
    } \
    __builtin_amdgcn_s_setprio(0); } while (0)

#define PUB()  __builtin_amdgcn_s_barrier()
#define PUBG() do { __builtin_amdgcn_s_barrier(); \
                    __builtin_amdgcn_sched_barrier(0); } while (0)
#define VMW4() asm volatile("s_waitcnt vmcnt(4)" ::: "memory")

#define STA(BUF, H) do { \
    gll16(pa[H][0], ldsA + (BUF) * 16384 + ((H) * 128 + wv * 16) * 64); pa[H][0] += 64; \
    gll16(pa[H][1], ldsA + (BUF) * 16384 + ((H) * 128 + wv * 16 + 8) * 64); pa[H][1] += 64; } while (0)

#define STB(BUF, H) do { \
    gll16(pb[H][0], ldsB + (BUF) * 16384 + ((H) * 128 + wv * 16) * 64); pb[H][0] += 64; \
    gll16(pb[H][1], ldsB + (BUF) * 16384 + ((H) * 128 + wv * 16 + 8) * 64); pb[H][1] += 64; } while (0)

#define FFN_KLOOP(NK) do { \
    STB(0, 0); STB(0, 1); STA(0, 0); STA(0, 1); STB(1, 0); STB(1, 1); \
    VMW4(); PUBG(); \
    for (int i_ = 0; i_ < (NK) / 2; ++i_) { \
        DSA(0, 0); DSB(0, 0); STA(1, 0);  PUB(); FFN_MFMA(0, 0); PUB(); \
        DSB(0, 1); STA(1, 1);             PUB(); FFN_MFMA(0, 1); PUBG(); \
        DSA(0, 1); STB(0, 0);             PUB(); FFN_MFMA(1, 0); PUB(); \
        STB(0, 1); VMW4();                PUB(); FFN_MFMA(1, 1); PUBG(); \
        DSA(1, 0); DSB(1, 0); STA(0, 0);  PUB(); FFN_MFMA(0, 0); PUB(); \
        DSB(1, 1); STA(0, 1);             PUB(); FFN_MFMA(0, 1); PUBG(); \
        DSA(1, 1); STB(1, 0);             PUB(); FFN_MFMA(1, 0); PUB(); \
        STB(1, 1); VMW4();                PUB(); FFN_MFMA(1, 1); PUBG(); \
    } } while (0)

// ---------------- grouped GEMM1 + w2-transpose tail blocks
__global__ __launch_bounds__(512, 2) void k_ffn1(
    const u16* __restrict__ xh, const u16* __restrict__ w1t,
    const float* __restrict__ b1, u16* __restrict__ hbuf,
    const int* __restrict__ ctrl, const int* __restrict__ lists,
    const float* __restrict__ w2, u16* __restrict__ w2t)
{
    extern __shared__ __align__(16) u16 lds[];
    int lid = blockIdx.x;
    int tid = threadIdx.x;
    if (lid >= G1BLK) {
        int tlid = lid - G1BLK;
        int e = tlid >> 6, by = tlid & 63;
        int half = tid >> 8, t2 = tid & 255;
        u16* mytile = lds + half * 4096;
#pragma unroll
        for (int c4 = 0; c4 < 2; ++c4)
            transpose_body4t(half * 2 + c4, by, e, w2, w2t, HDIM, CDIM, mytile, t2);
        return;
    }
    u16* ldsA = lds;                   // [2][256*64]
    u16* ldsB = lds + 2 * 256 * 64;    // [2][256*64]
    const half8* HA = reinterpret_cast<const half8*>(ldsA);
    const half8* HB = reinterpret_cast<const half8*>(ldsB);
    const int* cnt8 = ctrl + 8;
    int nt = sched_nt(cnt8);
    int nact = nt * 16;
    if (lid >= nact) return;
    int w = xcd_remap(lid, nact);
    int nt8 = nt * 8;
    int byh = w / nt8;
    int rem = w - byh * nt8;
    int t = rem >> 3;
    int by = byh * 8 + (rem & 7);
    int e, rt, prow, cnte;
    sched_tile(cnt8, t, e, rt, prow, cnte);
    int n0 = by * 256;
    int lane = tid & 63, wv = tid >> 6;
    int wm = wv >> 2, wn = wv & 3;
    int lr = lane >> 3;
    int chunk = (lane & 7) ^ lr;
    const int* lrow = lists + e * NTOK + rt * 256;
    int first_ent = lists[e * NTOK];
    const u16* pa[2][2]; const u16* pb[2][2];
#pragma unroll
    for (int h = 0; h < 2; ++h)
#pragma unroll
        for (int g = 0; g < 2; ++g) {
            int r = h * 128 + wv * 16 + g * 8 + lr;
            int ent = (rt * 256 + r < cnte) ? lrow[r] : first_ent;
            int tok = ent >> 1;
            pa[h][g] = xh + (size_t)tok * CDIM + chunk * 8;
            pb[h][g] = w1t + (size_t)e * HDIM * CDIM + (size_t)(n0 + r) * CDIM + chunk * 8;
        }
    int aIdx0 = wm * 1024 + (lane & 15) * 8 + ((lane >> 4) ^ (lane & 7));
    int aIdx1 = wm * 1024 + (lane & 15) * 8 + (((lane >> 4) + 4) ^ (lane & 7));
    int bIdx0 = wn * 512 + (lane & 15) * 8 + ((lane >> 4) ^ (lane & 7));
    int bIdx1 = wn * 512 + (lane & 15) * 8 + (((lane >> 4) + 4) ^ (lane & 7));
    f32x4 acc[8][4];
#pragma unroll
    for (int m = 0; m < 8; ++m)
#pragma unroll
        for (int n = 0; n < 4; ++n) acc[m][n] = f32x4{0.f, 0.f, 0.f, 0.f};
    half8 af[4][2], bf[2][2][2];

    FFN_KLOOP(16);   // K = 1024 = 16 tiles of 64

    const f32x4* b1v = reinterpret_cast<const f32x4*>(b1 + (size_t)e * HDIM);
    f32x4 bv[4];
#pragma unroll
    for (int n = 0; n < 4; ++n)
        bv[n] = b1v[(n0 + wn * 64 + n * 16) / 4 + (lane >> 4)];
#pragma unroll
    for (int m = 0; m < 8; ++m) {
        int grow = prow + rt * 256 + wm * 128 + m * 16 + (lane & 15);
        u16* hr = hbuf + (size_t)grow * HDIM + n0 + wn * 64 + (lane >> 4) * 4;
#pragma unroll
        for (int n = 0; n < 4; ++n) {
            ushort4 o;
#pragma unroll
            for (int j = 0; j < 4; ++j)
                ((u16*)&o)[j] = f2h(gelu_f(acc[m][n][j] + bv[n][j]));
            *reinterpret_cast<ushort4*>(hr + n * 16) = o;
        }
    }
}

// ---------------- grouped GEMM2 (mixed K-split): heavy=half-K, light=quarter-K
// Heavy blocks write quarter-slice 2kh and zero companion 2kh+1 (overlapped stores).
__global__ __launch_bounds__(512, 2) void k_ffn2(
    const u16* __restrict__ hbuf, const u16* __restrict__ w2t,
    const float* __restrict__ b2, u16* __restrict__ ybuf,
    const int* __restrict__ ctrl, const int* __restrict__ lists,
    const float2* __restrict__ rtw)
{
    extern __shared__ __align__(16) u16 lds[];
    u16* ldsA = lds;
    u16* ldsB = lds + 2 * 256 * 64;
    const half8* HA = reinterpret_cast<const half8*>(ldsA);
    const half8* HB = reinterpret_cast<const half8*>(ldsB);
    const int* cnt8 = ctrl + 8;
    int lid = blockIdx.x;
    int nt = sched_nt(cnt8);
    int U = nt * 8;
    int S = (U > 512) ? (U - 512) : 0;
    int Hh = U - S;
    int nact = Hh + 2 * S;
    if (lid >= nact) return;
    bool heavy = lid < Hh;
    int u, qh;
    if (heavy) { u = xcd_remap(lid, Hh); qh = 0; }
    else { int l = lid - Hh; u = Hh + (l >> 1); qh = l & 1; }
    int nt4 = nt * 4;
    int kh = u / nt4;
    int rem = u - kh * nt4;
    int t = rem >> 2;
    int by = rem & 3;
    int e, rt, prow, cnte;
    sched_tile(cnt8, t, e, rt, prow, cnte);
    int n0 = by * 256;
    int koff = kh * 2048 + qh * 1024;
    int tid = threadIdx.x, lane = tid & 63, wv = tid >> 6;
    int wm = wv >> 2, wn = wv & 3;
    int lr = lane >> 3;
    int chunk = (lane & 7) ^ lr;
    int rowbase = prow + rt * 256;
    const u16* pa[2][2]; const u16* pb[2][2];
#pragma unroll
    for (int h = 0; h < 2; ++h)
#pragma unroll
        for (int g = 0; g < 2; ++g) {
            int r = h * 128 + wv * 16 + g * 8 + lr;
            pa[h][g] = hbuf + (size_t)(rowbase + r) * HDIM + koff + chunk * 8;
            pb[h][g] = w2t + (size_t)e * CDIM * HDIM + (size_t)(n0 + r) * HDIM + koff + chunk * 8;
        }
    int aIdx0 = wm * 1024 + (lane & 15) * 8 + ((lane >> 4) ^ (lane & 7));
    int aIdx1 = wm * 1024 + (lane & 15) * 8 + (((lane >> 4) + 4) ^ (lane & 7));
    int bIdx0 = wn * 512 + (lane & 15) * 8 + ((lane >> 4) ^ (lane & 7));
    int bIdx1 = wn * 512 + (lane & 15) * 8 + (((lane >> 4) + 4) ^ (lane & 7));
    f32x4 acc[8][4];
#pragma unroll
    for (int m = 0; m < 8; ++m)
#pragma unroll
        for (int n = 0; n < 4; ++n) acc[m][n] = f32x4{0.f, 0.f, 0.f, 0.f};
    half8 af[4][2], bf[2][2][2];

    if (heavy) { FFN_KLOOP(32); } else { FFN_KLOOP(16); }

    const f32x4* b2v = reinterpret_cast<const f32x4*>(b2 + (size_t)e * CDIM);
    f32x4 bv[4];
#pragma unroll
    for (int n = 0; n < 4; ++n)
        bv[n] = b2v[(n0 + wn * 64 + n * 16) / 4 + (lane >> 4)];
    const int* lrow = lists + e * NTOK;
    const size_t SL = (size_t)NTOK * CDIM;
    int q = 2 * kh + qh;
#pragma unroll
    for (int m = 0; m < 8; ++m) {
        int p = rt * 256 + wm * 128 + m * 16 + (lane & 15);
        bool valid = p < cnte;
        int entry = valid ? lrow[p] : 0;
        float2 wpair = rtw[entry >> 1];
        float wgt = (entry & 1) ? wpair.y : wpair.x;
        size_t base = (size_t)(entry >> 1) * CDIM + n0 + wn * 64 + (lane >> 4) * 4;
        u16* yb = ybuf + ((size_t)((entry & 1) * 4 + q)) * SL + base;
        u16* yz = ybuf + ((size_t)((entry & 1) * 4 + 2 * kh + 1)) * SL + base;
#pragma unroll
        for (int n = 0; n < 4; ++n) {
            f32x4 v = acc[m][n];
            if (koff == 0) v = v + bv[n];
            v = v * wgt;
            ushort4 o;
#pragma unroll
            for (int j = 0; j < 4; ++j) ((u16*)&o)[j] = f2h(v[j]);
            if (valid) {
                *reinterpret_cast<ushort4*>(yb + n * 16) = o;
                if (heavy) {
                    ushort4 z; z.x = 0; z.y = 0; z.z = 0; z.w = 0;
                    *reinterpret_cast<ushort4*>(yz + n * 16) = z;
                }
            }
        }
    }
}

// ---------------- combine: out = sum of 8 fp16 ybuf slices
__global__ __launch_bounds__(256) void k_combine(
    const u16* __restrict__ ybuf, float* __restrict__ out)
{
    size_t i = ((size_t)blockIdx.x * 256 + threadIdx.x) * 4;
    const size_t S = (size_t)NTOK * CDIM;
    float s0 = 0.f, s1 = 0.f, s2 = 0.f, s3 = 0.f;
#pragma unroll
    for (int sl = 0; sl < 8; ++sl) {
        ushort4 h = *reinterpret_cast<const ushort4*>(ybuf + sl * S + i);
        s0 += h2f(h.x); s1 += h2f(h.y); s2 += h2f(h.z); s3 += h2f(h.w);
    }
    f32x4 o; o[0] = s0; o[1] = s1; o[2] = s2; o[3] = s3;
    *reinterpret_cast<f32x4*>(out + i) = o;
}

extern "C" void kernel_launch(void* const* d_in, const int* in_sizes, int n_in,
                              void* d_out, int out_size, void* d_ws, size_t ws_size,
                              hipStream_t stream)
{
    const float* x  = (const float*)d_in[0];
    const float* gw = (const float*)d_in[1];
    const float* gb = (const float*)d_in[2];
    const float* w1 = (const float*)d_in[3];
    const float* b1 = (const float*)d_in[4];
    const float* w2 = (const float*)d_in[5];
    const float* b2 = (const float*)d_in[6];
    float* out = (float*)d_out;
    char* ws = (char*)d_ws;

    size_t off = 0;
    int*    ctrl  = (int*)(ws + off);    off += 4096;
    float2* rtw   = (float2*)(ws + off); off += (size_t)NTOK * 8;
    int*    choice= (int*)(ws + off);    off += (size_t)NTOK * 4;
    int*    lists = (int*)(ws + off);    off += (size_t)NEXP * NTOK * 4;
    u16*    xh    = (u16*)(ws + off);    off += (size_t)NTOK * CDIM * 2;
    u16*    w1t   = (u16*)(ws + off);    off += (size_t)NEXP * CDIM * HDIM * 2;
    u16*    w2t   = (u16*)(ws + off);    off += (size_t)NEXP * CDIM * HDIM * 2;
    u16*    hbuf  = (u16*)(ws + off);    off += (size_t)MAXROWS2 * HDIM * 2;
    u16*    ybuf  = (u16*)(ws + off);    off += (size_t)8 * NTOK * CDIM * 2;
    (void)ws_size; (void)in_sizes; (void)n_in; (void)out_size;

    hipFuncSetAttribute((const void*)k_ffn1, hipFuncAttributeMaxDynamicSharedMemorySize, 131072);
    hipFuncSetAttribute((const void*)k_ffn2, hipFuncAttributeMaxDynamicSharedMemorySize, 131072);

    // z=0: route (atomic-free); z=1: w1 transpose
    k_prep<<<dim3(2048, 1, 2), 256, 0, stream>>>(x, gw, gb, xh, rtw, choice, w1, w1t);
    k_lists<<<dim3(NEXP), 256, 0, stream>>>(choice, ctrl + 8, lists);
    // GEMM1 blocks [0,1136) + w2-transpose tail blocks [1136,1648)
    k_ffn1<<<dim3(G1BLK + TRBLK), 512, 131072, stream>>>(xh, w1t, b1, hbuf, ctrl, lists,
                                                         w2, w2t);
    k_ffn2<<<dim3(G2BLK), 512, 131072, stream>>>(hbuf, w2t, b2, ybuf, ctrl, lists, rtw);
    k_combine<<<dim3(NTOK * CDIM / 1024), 256, 0, stream>>>(ybuf, out);
}